// Round 7
// baseline (300.742 us; speedup 1.0000x reference)
//
#include <hip/hip_runtime.h>
#include <hip/hip_cooperative_groups.h>
#include <math.h>

namespace cg = cooperative_groups;

#define BB 2
#define MM 8192
#define NN (BB * MM)
#define NBATCH (NN / 16)      // 1024 batches of 16 sorted points
#define NCELL 4096            // 16^3 morton cells per cloud

// ws layout (bytes):
#define PART_OFF   0          // 6*256 floats = 6144
#define RANK_OFF   8192       // NN ints = 65536
#define IDX_OFF    73728      // NN*16 ints = 1048576
#define PK_OFF     1122304    // NN float4 = 262144
#define SS_OFF     1384448    // NN floats = 65536
#define CELLID_OFF 1449984    // NN ints = 65536
#define CNT_OFF    1515520    // 2*NCELL ints = 32768
#define CUR_OFF    1548288    // 32768
#define BBLO_OFF   1581056    // NBATCH float4 = 16384
#define BBHI_OFF   1597440    // NBATCH float4 = 16384

__device__ __forceinline__ unsigned mort3(unsigned x, unsigned y, unsigned z) {
    unsigned m = 0;
#pragma unroll
    for (int i = 0; i < 4; ++i) {
        m |= ((x >> i) & 1u) << (3 * i);
        m |= ((y >> i) & 1u) << (3 * i + 1);
        m |= ((z >> i) & 1u) << (3 * i + 2);
    }
    return m;
}

__device__ __forceinline__ void sort16(unsigned (&a)[16]) {
    // Batcher odd-even mergesort, ascending (verified R3-R6, absmax 0)
#pragma unroll
    for (int p2 = 1; p2 < 16; p2 <<= 1) {
#pragma unroll
        for (int k2 = p2; k2 >= 1; k2 >>= 1) {
#pragma unroll
            for (int j2 = k2 % p2; j2 + k2 < 16; j2 += 2 * k2) {
#pragma unroll
                for (int i2 = 0; i2 < k2; ++i2) {
                    if (i2 + j2 + k2 < 16) {
                        if (((i2 + j2) / (2 * p2)) == ((i2 + j2 + k2) / (2 * p2))) {
                            unsigned x = a[i2 + j2], y = a[i2 + j2 + k2];
                            a[i2 + j2]      = min(x, y);
                            a[i2 + j2 + k2] = max(x, y);
                        }
                    }
                }
            }
        }
    }
}

__device__ __forceinline__ void truncmerge(unsigned (&slot)[16], const unsigned (&kb)[16]) {
    // lowest-16 of (sorted slot ∪ sorted kb), result sorted (verified R3-R6)
    unsigned m[16];
#pragma unroll
    for (int k = 0; k < 16; ++k) m[k] = min(slot[k], kb[15 - k]);
#pragma unroll
    for (int st = 8; st >= 1; st >>= 1) {
#pragma unroll
        for (int i = 0; i < 16; ++i) {
            if ((i & st) == 0) {
                unsigned lo = min(m[i], m[i + st]);
                unsigned hi = max(m[i], m[i + st]);
                m[i] = lo; m[i + st] = hi;
            }
        }
    }
#pragma unroll
    for (int k = 0; k < 16; ++k) slot[k] = m[k];
}

// Single cooperative kernel: 256 blocks x 1024 threads (co-resident: 69KB LDS
// allows 2 blocks/CU, so 256 blocks always fit). Phases separated by
// grid.sync(); kills ~8 inter-dispatch gaps of the 9-kernel pipeline.
__global__ __launch_bounds__(1024) void fused_kernel(
    const float* __restrict__ scores, const float* __restrict__ coords,
    float4* __restrict__ pk_s, float* __restrict__ s_s,
    int* __restrict__ cellid, int* __restrict__ cnt, int* __restrict__ cursor,
    float4* __restrict__ bb_lo, float4* __restrict__ bb_hi,
    int* __restrict__ out_idx, int* __restrict__ out_rank,
    float* __restrict__ partial, float* __restrict__ out)
{
    cg::grid_group grid = cg::this_grid();
    __shared__ unsigned lds_k[16][16][64];  // [wave][slot][lane]: conflict-free
    __shared__ int lds_i[16][64];
    __shared__ int wsum[16];
    __shared__ float redf[16][6];

    const int tid = threadIdx.x;
    const int blk = blockIdx.x;
    const int gid = blk * 1024 + tid;
    const int lane = tid & 63;
    const int wv = __builtin_amdgcn_readfirstlane(tid >> 6);

    // ---- Phase A: morton cell count (cnt pre-zeroed by hipMemsetAsync) ----
    if (tid < 64) {
        const int i = blk * 64 + tid;   // all 256 blocks participate
        float x = coords[3 * i], y = coords[3 * i + 1], z = coords[3 * i + 2];
        int cx = min(15, max(0, (int)floorf(x) + 8));
        int cy = min(15, max(0, (int)floorf(y) + 8));
        int cz = min(15, max(0, (int)floorf(z) + 8));
        int cid = (i >> 13) * NCELL + (int)mort3((unsigned)cx, (unsigned)cy, (unsigned)cz);
        cellid[i] = cid;
        atomicAdd(&cnt[cid], 1);
    }
    grid.sync();

    // ---- Phase B: exclusive scan over 8192 cells (block 0) ----
    if (blk == 0) {
        int v[8]; int run = 0;
#pragma unroll
        for (int i = 0; i < 8; ++i) { int t = cnt[tid * 8 + i]; v[i] = run; run += t; }
        int inc = run;
#pragma unroll
        for (int off = 1; off < 64; off <<= 1) {
            int y = __shfl_up(inc, off);
            if (lane >= off) inc += y;
        }
        int laneExcl = inc - run;
        if (lane == 63) wsum[wv] = inc;
        __syncthreads();
        int wbase = 0;
#pragma unroll
        for (int w = 0; w < 16; ++w) wbase += (w < wv) ? wsum[w] : 0;
        const int base = wbase + laneExcl;
#pragma unroll
        for (int i = 0; i < 8; ++i) cursor[tid * 8 + i] = base + v[i];
    }
    grid.sync();

    // ---- Phase C: scatter into morton order ----
    if (tid < 64) {
        const int i = blk * 64 + tid;
        int pos = atomicAdd(&cursor[cellid[i]], 1);
        float x = coords[3 * i], y = coords[3 * i + 1], z = coords[3 * i + 2];
        // MUST match dot ordering in knn so self-distance is exactly 0.
        float sq = fmaf(x, x, fmaf(y, y, z * z));
        pk_s[pos] = make_float4(x, y, z, sq);
        s_s[pos] = scores[i];
    }
    grid.sync();

    // ---- Phase D: per-batch bboxes (4 per block) ----
    if (tid < 4) {
        const int b = blk * 4 + tid;
        float4 c = pk_s[b * 16];
        float lx = c.x, ly = c.y, lz = c.z, hx = c.x, hy = c.y, hz = c.z;
#pragma unroll
        for (int i = 1; i < 16; ++i) {
            c = pk_s[b * 16 + i];
            lx = fminf(lx, c.x); ly = fminf(ly, c.y); lz = fminf(lz, c.z);
            hx = fmaxf(hx, c.x); hy = fmaxf(hy, c.y); hz = fmaxf(hz, c.z);
        }
        bb_lo[b] = make_float4(lx, ly, lz, 0.f);
        bb_hi[b] = make_float4(hx, hy, hz, 0.f);
    }
    grid.sync();

    // ---- Phase E: knn with TIGHT cooperative seed ----
    {
        const int qbase = blk * 64;
        const int cloudbase = (qbase >> 13) << 13;
        const float4 p = pk_s[qbase + lane];
        const int sb0 = (qbase - cloudbase) >> 4;   // first local batch (mult of 4)
        const int r = sb0 & 15;
        const int ownb = (wv >= r && wv < r + 4) ? (sb0 + (wv - r)) : -1;  // uniform
        const float4* __restrict__ pc = pk_s + cloudbase;
        const int bbase = cloudbase >> 4;

        unsigned slot[16];
#pragma unroll
        for (int k = 0; k < 16; ++k) slot[k] = 0x7F000000u + (unsigned)k;
        float t_f = 3.0e38f;

        auto batchU = [&](int bi) {
            unsigned kb[16];
#pragma unroll
            for (int i = 0; i < 16; ++i) {
                const int j = bi * 16 + i;          // uniform -> scalar loads
                const float4 c = pc[j];
                float dot = fmaf(p.x, c.x, fmaf(p.y, c.y, p.z * c.z));
                float d2  = fmaf(-2.0f, dot, p.w + c.w);   // exactly 0 for self
                kb[i] = (__float_as_uint(d2) & 0xFFFFE000u) | (unsigned)j;
            }
            sort16(kb);
            truncmerge(slot, kb);
            t_f = fminf(t_f, __uint_as_float((slot[15] & 0xFFFFE000u) + 0x2000u));
        };

        // owners process their one local batch
        if (ownb >= 0) batchU(ownb);
#pragma unroll
        for (int k = 0; k < 16; ++k) lds_k[wv][k][lane] = slot[k];
        __syncthreads();
        // every lane merges the 4 owner lists -> true top-16 of 64 local points
        unsigned mg[16];
#pragma unroll
        for (int k = 0; k < 16; ++k) mg[k] = lds_k[r][k][lane];
#pragma unroll
        for (int w2 = 1; w2 < 4; ++w2) {
            unsigned ob[16];
#pragma unroll
            for (int k = 0; k < 16; ++k) ob[k] = lds_k[r + w2][k][lane];
            truncmerge(mg, ob);
        }
        __syncthreads();   // all lds_k reads done before any later write
        // wave r carries the merged list; other waves reset (keys subsumed:
        // dropped keys are dominated by 16 better local keys -> never top-16)
        if (wv == r) {
#pragma unroll
            for (int k = 0; k < 16; ++k) slot[k] = mg[k];
        } else {
#pragma unroll
            for (int k = 0; k < 16; ++k) slot[k] = 0x7F000000u + (unsigned)k;
        }
        t_f = __uint_as_float((mg[15] & 0xFFFFE000u) + 0x2000u);  // tight, tie-inclusive

        // bound scan with inline hot processing (R5 structure, scalar loads)
        float4 lo = bb_lo[bbase + wv];
        float4 hi = bb_hi[bbase + wv];
        for (int k2 = 0; k2 < 32; ++k2) {
            const int bi = wv + (k2 << 4);
            float4 lo_n, hi_n;
            if (k2 + 1 < 32) {                      // uniform branch
                lo_n = bb_lo[bbase + bi + 16];
                hi_n = bb_hi[bbase + bi + 16];
            }
            if (bi != ownb) {                       // uniform skip (seeded)
                float dx = fmaxf(fmaxf(lo.x - p.x, p.x - hi.x), 0.f);
                float dy = fmaxf(fmaxf(lo.y - p.y, p.y - hi.y), 0.f);
                float dz = fmaxf(fmaxf(lo.z - p.z, p.z - hi.z), 0.f);
                float lb = fmaf(dx, dx, fmaf(dy, dy, dz * dz));
                if (__any(fmaf(lb, 0.999f, -1e-5f) < t_f)) batchU(bi);
            }
            lo = lo_n; hi = hi_n;
        }

#pragma unroll
        for (int k = 0; k < 16; ++k) lds_k[wv][k][lane] = slot[k];

        // tree merge 16 -> 1 sorted lists (verified R3-R6)
        for (int half = 8; half >= 1; half >>= 1) {
            __syncthreads();
            if (wv < half) {
                unsigned a[16], m[16];
#pragma unroll
                for (int k = 0; k < 16; ++k) a[k] = lds_k[wv][k][lane];
#pragma unroll
                for (int k = 0; k < 16; ++k) m[k] = min(a[k], lds_k[wv + half][15 - k][lane]);
#pragma unroll
                for (int st = 8; st >= 1; st >>= 1) {
#pragma unroll
                    for (int i = 0; i < 16; ++i) {
                        if ((i & st) == 0) {
                            unsigned lo2 = min(m[i], m[i + st]);
                            unsigned hi2 = max(m[i], m[i + st]);
                            m[i] = lo2; m[i + st] = hi2;
                        }
                    }
                }
#pragma unroll
                for (int k = 0; k < 16; ++k) lds_k[wv][k][lane] = m[k];
            }
        }
        __syncthreads();
        if (wv == 0) {
#pragma unroll
            for (int k = 0; k < 16; ++k)
                out_idx[(qbase + lane) * 16 + k] = (int)(lds_k[0][k][lane] & 0x1FFFu) + cloudbase;
        }
    }

    // ---- Phase F: rank (verbatim R5 rank body; only needs s_s) ----
    {
        __syncthreads();
        const int qbase = blk * 64;
        const int cloudbase = (qbase >> 13) << 13;
        const float s = s_s[qbase + lane];
        const float* __restrict__ sc = s_s + cloudbase;
        int rank = 0;
        const int j0 = wv * 512;
        for (int jj = 0; jj < 512; jj += 16) {
#pragma unroll
            for (int i = 0; i < 16; ++i) {
                rank += (sc[j0 + jj + i] < s) ? 1 : 0;   // uniform -> scalar loads
            }
        }
        lds_i[wv][lane] = rank;
        __syncthreads();
        if (wv == 0) {
            int rsum = 0;
#pragma unroll
            for (int w = 0; w < 16; ++w) rsum += lds_i[w][lane];
            out_rank[qbase + lane] = rsum;
        }
    }
    grid.sync();

    // ---- Phase G: loss terms (one thread per (q,k) pair; gid == NN*16) ----
    {
        const int t = gid;
        const int q = t >> 4, kk = t & 15;
        const int nb = out_idx[t];
        const float s  = s_s[q];
        const float sn = s_s[nb];
        const float diff = fabsf(s - sn);
        const float sim = 1.0f - diff;
        const float sg = 1.0f / (1.0f + expf(-2.0f * sim));

        float a_wd = 0.f, a_w = 0.f, a_pos = 0.f, a_neg = 0.f, snk = 0.f;
        if (kk < 8) {
            float4 pq = pk_s[q];
            float4 pn = pk_s[nb];
            float dx = pq.x - pn.x, dy = pq.y - pn.y, dz = pq.z - pn.z;
            float d = sqrtf(dx * dx + dy * dy + dz * dz);
            float w = expf(-10.0f * d);
            a_wd = w * diff * diff;
            a_w  = w;
            a_pos = logf(sg + 1e-8f);
            snk = sn;
        } else {
            a_neg = logf(1.0f - sg + 1e-8f);
        }

        float nsum = snk;
#pragma unroll
        for (int off = 1; off < 16; off <<= 1) nsum += __shfl_xor(nsum, off);

        float a_sm = 0.f, a_di = 0.f;
        if (kk == 0) {
            float t1 = s - nsum * 0.125f;
            a_sm = t1 * t1;
            float t2 = s - (float)out_rank[q] * (1.0f / 8191.0f);
            a_di = t2 * t2;
        }

#pragma unroll
        for (int off = 1; off < 64; off <<= 1) {
            a_wd  += __shfl_xor(a_wd, off);
            a_w   += __shfl_xor(a_w, off);
            a_pos += __shfl_xor(a_pos, off);
            a_neg += __shfl_xor(a_neg, off);
            a_sm  += __shfl_xor(a_sm, off);
            a_di  += __shfl_xor(a_di, off);
        }
        if (lane == 0) {
            redf[wv][0] = a_wd; redf[wv][1] = a_w; redf[wv][2] = a_pos;
            redf[wv][3] = a_neg; redf[wv][4] = a_sm; redf[wv][5] = a_di;
        }
        __syncthreads();
        if (tid < 6) {
            float v = 0.f;
#pragma unroll
            for (int w = 0; w < 16; ++w) v += redf[w][tid];
            partial[tid * 256 + blk] = v;
        }
    }
    grid.sync();

    // ---- Phase H: final reduce (block 0) ----
    if (blk == 0) {
        if (tid < 256) {
            float a[6];
#pragma unroll
            for (int term = 0; term < 6; ++term) a[term] = partial[term * 256 + tid];
#pragma unroll
            for (int off = 1; off < 64; off <<= 1) {
#pragma unroll
                for (int term = 0; term < 6; ++term) a[term] += __shfl_xor(a[term], off);
            }
            if (lane == 0) {
#pragma unroll
                for (int term = 0; term < 6; ++term) redf[wv][term] = a[term];
            }
        }
        __syncthreads();
        if (tid == 0) {
            float acc[6];
#pragma unroll
            for (int term = 0; term < 6; ++term)
                acc[term] = redf[0][term] + redf[1][term] + redf[2][term] + redf[3][term];
            float l_loc = acc[0] / fmaxf(acc[1], 1e-8f);
            float l_pos = -acc[2] / (float)(NN * 8);
            float l_neg = -acc[3] / (float)(NN * 8);
            float l_sm  = acc[4] / (float)NN;
            float l_di  = acc[5] / (float)NN;
            out[0] = l_loc + 0.5f * (l_pos + l_neg) + 0.3f * l_di + 0.2f * l_sm;
        }
    }
}

extern "C" void kernel_launch(void* const* d_in, const int* in_sizes, int n_in,
                              void* d_out, int out_size, void* d_ws, size_t ws_size,
                              hipStream_t stream) {
    const float* scores = (const float*)d_in[0];
    const float* coords = (const float*)d_in[1];
    (void)in_sizes; (void)n_in; (void)out_size; (void)ws_size;

    char* ws = (char*)d_ws;
    float*  part  = (float*)(ws + PART_OFF);
    int*    rank  = (int*)(ws + RANK_OFF);
    int*    knn   = (int*)(ws + IDX_OFF);
    float4* pk_s  = (float4*)(ws + PK_OFF);
    float*  s_s   = (float*)(ws + SS_OFF);
    int*    cellid= (int*)(ws + CELLID_OFF);
    int*    cnt   = (int*)(ws + CNT_OFF);
    int*    cursor= (int*)(ws + CUR_OFF);
    float4* bb_lo = (float4*)(ws + BBLO_OFF);
    float4* bb_hi = (float4*)(ws + BBHI_OFF);
    float*  out   = (float*)d_out;

    hipMemsetAsync(cnt, 0, 2 * NCELL * sizeof(int), stream);

    void* kargs[] = {
        (void*)&scores, (void*)&coords, (void*)&pk_s, (void*)&s_s,
        (void*)&cellid, (void*)&cnt, (void*)&cursor,
        (void*)&bb_lo, (void*)&bb_hi, (void*)&knn, (void*)&rank,
        (void*)&part, (void*)&out
    };
    hipLaunchCooperativeKernel((const void*)fused_kernel, dim3(256), dim3(1024),
                               kargs, 0, stream);
}

// Round 8
// 210.954 us; speedup vs baseline: 1.4256x; 1.4256x over previous
//
#include <hip/hip_runtime.h>
#include <hip/hip_bf16.h>
#include <math.h>

#define BB 2
#define MM 8192
#define NN (BB * MM)
#define NBATCH (NN / 16)      // 1024 batches of 16 sorted points
#define NCELL 4096            // 16^3 morton cells per cloud
#define LOSS_BLOCKS 1024

// ws layout (bytes):
#define PART_OFF   0          // 6 * LOSS_BLOCKS floats = 24576
#define DONE_OFF   24576      // 1 int (zeroed each launch)
#define RANK_OFF   24640      // NN ints = 65536
#define IDX_OFF    90176      // NN*16 ints = 1048576
#define PK_OFF     1138752    // NN float4 = 262144
#define SS_OFF     1400896    // NN floats = 65536
#define CELLID_OFF 1466432    // NN ints = 65536
#define CNT_OFF    1531968    // 2*NCELL ints = 32768
#define CUR_OFF    1564736    // 32768
#define BBLO_OFF   1597504    // NBATCH float4 = 16384
#define BBHI_OFF   1613888    // NBATCH float4 = 16384

__device__ __forceinline__ unsigned mort3(unsigned x, unsigned y, unsigned z) {
    unsigned m = 0;
#pragma unroll
    for (int i = 0; i < 4; ++i) {
        m |= ((x >> i) & 1u) << (3 * i);
        m |= ((y >> i) & 1u) << (3 * i + 1);
        m |= ((z >> i) & 1u) << (3 * i + 2);
    }
    return m;
}

__global__ void count_kernel(const float* __restrict__ coords, int* __restrict__ cellid,
                             int* __restrict__ cnt) {
    int i = blockIdx.x * 256 + threadIdx.x;
    if (i < NN) {
        float x = coords[3 * i], y = coords[3 * i + 1], z = coords[3 * i + 2];
        int cx = min(15, max(0, (int)floorf(x) + 8));
        int cy = min(15, max(0, (int)floorf(y) + 8));
        int cz = min(15, max(0, (int)floorf(z) + 8));
        int cid = (i >> 13) * NCELL + (int)mort3((unsigned)cx, (unsigned)cy, (unsigned)cz);
        cellid[i] = cid;
        atomicAdd(&cnt[cid], 1);
    }
}

// exclusive prefix over 8192 cell counts -> cursor (scatter start positions)
__global__ __launch_bounds__(1024) void scan_kernel(const int* __restrict__ cnt,
                                                    int* __restrict__ cursor) {
    __shared__ int wsum[16];
    const int tid = threadIdx.x, lane = tid & 63, wv = tid >> 6;
    int v[8]; int run = 0;
#pragma unroll
    for (int i = 0; i < 8; ++i) { int t = cnt[tid * 8 + i]; v[i] = run; run += t; }
    int inc = run;
#pragma unroll
    for (int off = 1; off < 64; off <<= 1) {
        int y = __shfl_up(inc, off);
        if (lane >= off) inc += y;
    }
    int laneExcl = inc - run;
    if (lane == 63) wsum[wv] = inc;
    __syncthreads();
    int wbase = 0;
#pragma unroll
    for (int w = 0; w < 16; ++w) wbase += (w < wv) ? wsum[w] : 0;
    const int base = wbase + laneExcl;
#pragma unroll
    for (int i = 0; i < 8; ++i) cursor[tid * 8 + i] = base + v[i];
}

__global__ void scatter_kernel(const float* __restrict__ coords, const float* __restrict__ scores,
                               const int* __restrict__ cellid, int* __restrict__ cursor,
                               float4* __restrict__ pk_s, float* __restrict__ s_s) {
    int i = blockIdx.x * 256 + threadIdx.x;
    if (i < NN) {
        int pos = atomicAdd(&cursor[cellid[i]], 1);
        float x = coords[3 * i], y = coords[3 * i + 1], z = coords[3 * i + 2];
        // MUST match dot ordering in knn_kernel so self-distance is exactly 0.
        float sq = fmaf(x, x, fmaf(y, y, z * z));
        pk_s[pos] = make_float4(x, y, z, sq);
        s_s[pos] = scores[i];
    }
}

__global__ void bbox_kernel(const float4* __restrict__ pk_s, float4* __restrict__ bb_lo,
                            float4* __restrict__ bb_hi) {
    int b = blockIdx.x * 256 + threadIdx.x;
    if (b < NBATCH) {
        float4 c = pk_s[b * 16];
        float lx = c.x, ly = c.y, lz = c.z, hx = c.x, hy = c.y, hz = c.z;
#pragma unroll
        for (int i = 1; i < 16; ++i) {
            c = pk_s[b * 16 + i];
            lx = fminf(lx, c.x); ly = fminf(ly, c.y); lz = fminf(lz, c.z);
            hx = fmaxf(hx, c.x); hy = fmaxf(hy, c.y); hz = fmaxf(hz, c.z);
        }
        bb_lo[b] = make_float4(lx, ly, lz, 0.f);
        bb_hi[b] = make_float4(hx, hy, hz, 0.f);
    }
}

__device__ __forceinline__ void sort16(unsigned (&a)[16]) {
    // Batcher odd-even mergesort, ascending (verified R3-R7, absmax 0)
#pragma unroll
    for (int p2 = 1; p2 < 16; p2 <<= 1) {
#pragma unroll
        for (int k2 = p2; k2 >= 1; k2 >>= 1) {
#pragma unroll
            for (int j2 = k2 % p2; j2 + k2 < 16; j2 += 2 * k2) {
#pragma unroll
                for (int i2 = 0; i2 < k2; ++i2) {
                    if (i2 + j2 + k2 < 16) {
                        if (((i2 + j2) / (2 * p2)) == ((i2 + j2 + k2) / (2 * p2))) {
                            unsigned x = a[i2 + j2], y = a[i2 + j2 + k2];
                            a[i2 + j2]      = min(x, y);
                            a[i2 + j2 + k2] = max(x, y);
                        }
                    }
                }
            }
        }
    }
}

__device__ __forceinline__ void truncmerge(unsigned (&slot)[16], const unsigned (&kb)[16]) {
    // lowest-16 of (sorted slot ∪ sorted kb), result sorted (verified R3-R7)
    unsigned m[16];
#pragma unroll
    for (int k = 0; k < 16; ++k) m[k] = min(slot[k], kb[15 - k]);
#pragma unroll
    for (int st = 8; st >= 1; st >>= 1) {
#pragma unroll
        for (int i = 0; i < 16; ++i) {
            if ((i & st) == 0) {
                unsigned lo = min(m[i], m[i + st]);
                unsigned hi = max(m[i], m[i + st]);
                m[i] = lo; m[i + st] = hi;
            }
        }
    }
#pragma unroll
    for (int k = 0; k < 16; ++k) slot[k] = m[k];
}

// R5 structure + TIGHT cooperative seed (logic verified in R7, absmax 0):
// owner waves each process one of the 4 local batches; all lanes merge the 4
// owner lists -> true top-16 of 64 local points -> threshold ~1.1x true r16
// instead of ~1.8x -> hot-batch union per wave ~12 -> ~4. Rank fused as tail.
__global__ __launch_bounds__(1024) void knn_kernel(const float4* __restrict__ pk_s,
                                                   const float* __restrict__ s_s,
                                                   const float4* __restrict__ bb_lo,
                                                   const float4* __restrict__ bb_hi,
                                                   int* __restrict__ out_idx,
                                                   int* __restrict__ out_rank) {
    __shared__ unsigned lds_k[16][16][64];  // [wave][slot][lane]: conflict-free
    __shared__ int lds_i[16][64];
    const int tid = threadIdx.x, lane = tid & 63;
    const int wv = __builtin_amdgcn_readfirstlane(tid >> 6);
    const int qbase = blockIdx.x * 64;
    const int cloudbase = (qbase >> 13) << 13;
    const float4 p = pk_s[qbase + lane];
    const int sb0 = (qbase - cloudbase) >> 4;      // first local batch (mult of 4)
    const int r = sb0 & 15;
    const int ownb = (wv >= r && wv < r + 4) ? (sb0 + (wv - r)) : -1;  // uniform
    const float4* __restrict__ pc = pk_s + cloudbase;
    const int bbase = cloudbase >> 4;

    unsigned slot[16];
#pragma unroll
    for (int k = 0; k < 16; ++k) slot[k] = 0x7F000000u + (unsigned)k;  // > any real key
    float t_f = 3.0e38f;

    auto batchU = [&](int bi) {
        unsigned kb[16];
#pragma unroll
        for (int i = 0; i < 16; ++i) {
            const int j = bi * 16 + i;             // uniform -> scalar loads
            const float4 c = pc[j];
            float dot = fmaf(p.x, c.x, fmaf(p.y, c.y, p.z * c.z));
            float d2  = fmaf(-2.0f, dot, p.w + c.w);   // exactly 0 for self
            kb[i] = (__float_as_uint(d2) & 0xFFFFE000u) | (unsigned)j;
        }
        sort16(kb);
        truncmerge(slot, kb);
        t_f = fminf(t_f, __uint_as_float((slot[15] & 0xFFFFE000u) + 0x2000u));
    };

    // --- tight cooperative seed (verified R7) ---
    if (ownb >= 0) batchU(ownb);
#pragma unroll
    for (int k = 0; k < 16; ++k) lds_k[wv][k][lane] = slot[k];
    __syncthreads();
    unsigned mg[16];
#pragma unroll
    for (int k = 0; k < 16; ++k) mg[k] = lds_k[r][k][lane];
#pragma unroll
    for (int w2 = 1; w2 < 4; ++w2) {
        unsigned ob[16];
#pragma unroll
        for (int k = 0; k < 16; ++k) ob[k] = lds_k[r + w2][k][lane];
        truncmerge(mg, ob);
    }
    __syncthreads();   // all lds_k reads done before later writes
    // wave r carries the merged list; other waves reset (dropped keys are
    // dominated by 16 better local keys -> can never be global top-16)
    if (wv == r) {
#pragma unroll
        for (int k = 0; k < 16; ++k) slot[k] = mg[k];
    } else {
#pragma unroll
        for (int k = 0; k < 16; ++k) slot[k] = 0x7F000000u + (unsigned)k;
    }
    t_f = __uint_as_float((mg[15] & 0xFFFFE000u) + 0x2000u);  // tight, tie-inclusive

    // --- bound scan with inline hot processing (R5 structure) ---
    float4 lo = bb_lo[bbase + wv];
    float4 hi = bb_hi[bbase + wv];
    for (int k2 = 0; k2 < 32; ++k2) {
        const int bi = wv + (k2 << 4);
        float4 lo_n, hi_n;
        if (k2 + 1 < 32) {                         // uniform branch
            lo_n = bb_lo[bbase + bi + 16];
            hi_n = bb_hi[bbase + bi + 16];
        }
        if (bi != ownb) {                          // uniform skip (seeded)
            float dx = fmaxf(fmaxf(lo.x - p.x, p.x - hi.x), 0.f);
            float dy = fmaxf(fmaxf(lo.y - p.y, p.y - hi.y), 0.f);
            float dz = fmaxf(fmaxf(lo.z - p.z, p.z - hi.z), 0.f);
            float lb = fmaf(dx, dx, fmaf(dy, dy, dz * dz));
            if (__any(fmaf(lb, 0.999f, -1e-5f) < t_f)) batchU(bi);
        }
        lo = lo_n; hi = hi_n;
    }

#pragma unroll
    for (int k = 0; k < 16; ++k) lds_k[wv][k][lane] = slot[k];

    // tree merge 16 -> 1 sorted lists (verified R3-R7)
    for (int half = 8; half >= 1; half >>= 1) {
        __syncthreads();
        if (wv < half) {
            unsigned a[16], m[16];
#pragma unroll
            for (int k = 0; k < 16; ++k) a[k] = lds_k[wv][k][lane];
#pragma unroll
            for (int k = 0; k < 16; ++k) m[k] = min(a[k], lds_k[wv + half][15 - k][lane]);
#pragma unroll
            for (int st = 8; st >= 1; st >>= 1) {
#pragma unroll
                for (int i = 0; i < 16; ++i) {
                    if ((i & st) == 0) {
                        unsigned lo2 = min(m[i], m[i + st]);
                        unsigned hi2 = max(m[i], m[i + st]);
                        m[i] = lo2; m[i + st] = hi2;
                    }
                }
            }
#pragma unroll
            for (int k = 0; k < 16; ++k) lds_k[wv][k][lane] = m[k];
        }
    }
    __syncthreads();
    if (wv == 0) {
#pragma unroll
        for (int k = 0; k < 16; ++k)
            out_idx[(qbase + lane) * 16 + k] = (int)(lds_k[0][k][lane] & 0x1FFFu) + cloudbase;
    }

    // --- rank tail (verbatim R5 rank body; independent of knn results) ---
    {
        const float s = s_s[qbase + lane];
        const float* __restrict__ sc = s_s + cloudbase;
        int rank = 0;
        const int j0 = wv * 512;
        for (int jj = 0; jj < 512; jj += 16) {
#pragma unroll
            for (int i = 0; i < 16; ++i) {
                rank += (sc[j0 + jj + i] < s) ? 1 : 0;   // uniform -> scalar loads
            }
        }
        lds_i[wv][lane] = rank;
        __syncthreads();
        if (wv == 0) {
            int rsum = 0;
#pragma unroll
            for (int w = 0; w < 16; ++w) rsum += lds_i[w][lane];
            out_rank[qbase + lane] = rsum;
        }
    }
}

// one thread per (query,k) pair; block partials + last-block finalize
__global__ __launch_bounds__(256) void loss_kernel(const float* __restrict__ s_s,
                                                   const float4* __restrict__ pk_s,
                                                   const int* __restrict__ knn,
                                                   const int* __restrict__ rank,
                                                   float* __restrict__ partial,
                                                   int* __restrict__ done,
                                                   float* __restrict__ out) {
    __shared__ float red[4][6];
    __shared__ int isLast;
    const int t = blockIdx.x * 256 + threadIdx.x;
    const int q = t >> 4, k = t & 15;
    const int nb = knn[t];
    const float s  = s_s[q];
    const float sn = s_s[nb];
    const float diff = fabsf(s - sn);
    const float sim = 1.0f - diff;
    const float sg = 1.0f / (1.0f + expf(-2.0f * sim));

    float a_wd = 0.f, a_w = 0.f, a_pos = 0.f, a_neg = 0.f, snk = 0.f;
    if (k < 8) {
        float4 pq = pk_s[q];
        float4 pn = pk_s[nb];
        float dx = pq.x - pn.x, dy = pq.y - pn.y, dz = pq.z - pn.z;
        float d = sqrtf(dx * dx + dy * dy + dz * dz);
        float w = expf(-10.0f * d);
        a_wd = w * diff * diff;
        a_w  = w;
        a_pos = logf(sg + 1e-8f);
        snk = sn;
    } else {
        a_neg = logf(1.0f - sg + 1e-8f);
    }

    float nsum = snk;
#pragma unroll
    for (int off = 1; off < 16; off <<= 1) nsum += __shfl_xor(nsum, off);

    float a_sm = 0.f, a_di = 0.f;
    if (k == 0) {
        float t1 = s - nsum * 0.125f;
        a_sm = t1 * t1;
        float t2 = s - (float)rank[q] * (1.0f / 8191.0f);
        a_di = t2 * t2;
    }

#pragma unroll
    for (int off = 1; off < 64; off <<= 1) {
        a_wd  += __shfl_xor(a_wd, off);
        a_w   += __shfl_xor(a_w, off);
        a_pos += __shfl_xor(a_pos, off);
        a_neg += __shfl_xor(a_neg, off);
        a_sm  += __shfl_xor(a_sm, off);
        a_di  += __shfl_xor(a_di, off);
    }
    const int wv = threadIdx.x >> 6;
    if ((threadIdx.x & 63) == 0) {
        red[wv][0] = a_wd; red[wv][1] = a_w; red[wv][2] = a_pos;
        red[wv][3] = a_neg; red[wv][4] = a_sm; red[wv][5] = a_di;
    }
    __syncthreads();
    if (threadIdx.x < 6) {
        float v = red[0][threadIdx.x] + red[1][threadIdx.x] +
                  red[2][threadIdx.x] + red[3][threadIdx.x];
        partial[threadIdx.x * LOSS_BLOCKS + blockIdx.x] = v;
    }
    // last-block finalize (standard pattern: fence + device-scope counter)
    __threadfence();
    if (threadIdx.x == 0) isLast = (atomicAdd(done, 1) == LOSS_BLOCKS - 1);
    __syncthreads();
    if (isLast) {
        __threadfence();   // acquire: make all partials visible
        float a[6];
#pragma unroll
        for (int term = 0; term < 6; ++term) {
            float v = 0.f;
#pragma unroll
            for (int i = 0; i < 4; ++i)
                v += partial[term * LOSS_BLOCKS + threadIdx.x * 4 + i];
            a[term] = v;
        }
#pragma unroll
        for (int off = 1; off < 64; off <<= 1) {
#pragma unroll
            for (int term = 0; term < 6; ++term) a[term] += __shfl_xor(a[term], off);
        }
        if ((threadIdx.x & 63) == 0) {
#pragma unroll
            for (int term = 0; term < 6; ++term) red[wv][term] = a[term];
        }
        __syncthreads();
        if (threadIdx.x == 0) {
            float acc[6];
#pragma unroll
            for (int term = 0; term < 6; ++term)
                acc[term] = red[0][term] + red[1][term] + red[2][term] + red[3][term];
            float l_loc = acc[0] / fmaxf(acc[1], 1e-8f);
            float l_pos = -acc[2] / (float)(NN * 8);
            float l_neg = -acc[3] / (float)(NN * 8);
            float l_sm  = acc[4] / (float)NN;
            float l_di  = acc[5] / (float)NN;
            out[0] = l_loc + 0.5f * (l_pos + l_neg) + 0.3f * l_di + 0.2f * l_sm;
        }
    }
}

extern "C" void kernel_launch(void* const* d_in, const int* in_sizes, int n_in,
                              void* d_out, int out_size, void* d_ws, size_t ws_size,
                              hipStream_t stream) {
    const float* scores = (const float*)d_in[0];
    const float* coords = (const float*)d_in[1];
    (void)in_sizes; (void)n_in; (void)out_size; (void)ws_size;

    char* ws = (char*)d_ws;
    float*  part  = (float*)(ws + PART_OFF);
    int*    done  = (int*)(ws + DONE_OFF);
    int*    rank  = (int*)(ws + RANK_OFF);
    int*    knn   = (int*)(ws + IDX_OFF);
    float4* pk_s  = (float4*)(ws + PK_OFF);
    float*  s_s   = (float*)(ws + SS_OFF);
    int*    cellid= (int*)(ws + CELLID_OFF);
    int*    cnt   = (int*)(ws + CNT_OFF);
    int*    cursor= (int*)(ws + CUR_OFF);
    float4* bb_lo = (float4*)(ws + BBLO_OFF);
    float4* bb_hi = (float4*)(ws + BBHI_OFF);
    float*  out   = (float*)d_out;

    hipMemsetAsync(done, 0, sizeof(int), stream);
    hipMemsetAsync(cnt, 0, 2 * NCELL * sizeof(int), stream);
    count_kernel<<<64, 256, 0, stream>>>(coords, cellid, cnt);
    scan_kernel<<<1, 1024, 0, stream>>>(cnt, cursor);
    scatter_kernel<<<64, 256, 0, stream>>>(coords, scores, cellid, cursor, pk_s, s_s);
    bbox_kernel<<<4, 256, 0, stream>>>(pk_s, bb_lo, bb_hi);
    knn_kernel<<<256, 1024, 0, stream>>>(pk_s, s_s, bb_lo, bb_hi, knn, rank);
    loss_kernel<<<LOSS_BLOCKS, 256, 0, stream>>>(s_s, pk_s, knn, rank, part, done, out);
}

// Round 9
// 150.246 us; speedup vs baseline: 2.0017x; 1.4041x over previous
//
#include <hip/hip_runtime.h>
#include <hip/hip_bf16.h>
#include <math.h>

#define BB 2
#define MM 8192
#define NN (BB * MM)
#define NBATCH (NN / 16)      // 1024 batches of 16 sorted points
#define NCELL 4096            // 16^3 morton cells per cloud
#define LOSS_BLOCKS 1024

// ws layout (bytes):
#define PART_OFF   0          // 6 * LOSS_BLOCKS floats = 24576
#define RANK_OFF   24576      // NN ints = 65536
#define IDX_OFF    90112      // NN*16 ints = 1048576
#define PK_OFF     1138688    // NN float4 = 262144
#define SS_OFF     1400832    // NN floats = 65536
#define CELLID_OFF 1466368    // NN ints = 65536
#define CUR_OFF    1531904    // 2*NCELL ints = 32768
#define BBLO_OFF   1564672    // NBATCH uint4 = 16384
#define BBHI_OFF   1581056    // NBATCH uint4 = 16384

// order-preserving float<->uint transform (for atomicMin/Max bboxes)
__device__ __forceinline__ unsigned fenc(float f) {
    unsigned u = __float_as_uint(f);
    return (u & 0x80000000u) ? ~u : (u | 0x80000000u);
}
__device__ __forceinline__ float fdec(unsigned u) {
    return __uint_as_float((u & 0x80000000u) ? (u & 0x7FFFFFFFu) : ~u);
}

__device__ __forceinline__ unsigned mort3(unsigned x, unsigned y, unsigned z) {
    unsigned m = 0;
#pragma unroll
    for (int i = 0; i < 4; ++i) {
        m |= ((x >> i) & 1u) << (3 * i);
        m |= ((y >> i) & 1u) << (3 * i + 1);
        m |= ((z >> i) & 1u) << (3 * i + 2);
    }
    return m;
}

// Single block: LDS cell histogram (no memset, no global atomics) + exclusive
// scan -> cursor; also inits bbox arrays (min=0xFFFFFFFF, max=0).
__global__ __launch_bounds__(1024) void countscan_kernel(const float* __restrict__ coords,
                                                         int* __restrict__ cellid,
                                                         int* __restrict__ cursor,
                                                         unsigned* __restrict__ bblo,
                                                         unsigned* __restrict__ bbhi) {
    __shared__ int scnt[2 * NCELL];   // 32 KB
    __shared__ int wsum[16];
    const int tid = threadIdx.x, lane = tid & 63, wv = tid >> 6;
#pragma unroll
    for (int j = 0; j < 8; ++j) scnt[tid + 1024 * j] = 0;
    __syncthreads();
#pragma unroll
    for (int j = 0; j < 16; ++j) {
        const int i = tid + 1024 * j;              // coalesced
        float x = coords[3 * i], y = coords[3 * i + 1], z = coords[3 * i + 2];
        int cx = min(15, max(0, (int)floorf(x) + 8));
        int cy = min(15, max(0, (int)floorf(y) + 8));
        int cz = min(15, max(0, (int)floorf(z) + 8));
        int cid = (i >> 13) * NCELL + (int)mort3((unsigned)cx, (unsigned)cy, (unsigned)cz);
        cellid[i] = cid;
        atomicAdd(&scnt[cid], 1);
    }
    __syncthreads();
    int v[8]; int run = 0;
#pragma unroll
    for (int i = 0; i < 8; ++i) { int t = scnt[tid * 8 + i]; v[i] = run; run += t; }
    int inc = run;
#pragma unroll
    for (int off = 1; off < 64; off <<= 1) {
        int y = __shfl_up(inc, off);
        if (lane >= off) inc += y;
    }
    int laneExcl = inc - run;
    if (lane == 63) wsum[wv] = inc;
    __syncthreads();
    int wbase = 0;
#pragma unroll
    for (int w = 0; w < 16; ++w) wbase += (w < wv) ? wsum[w] : 0;
    const int base = wbase + laneExcl;
#pragma unroll
    for (int i = 0; i < 8; ++i) cursor[tid * 8 + i] = base + v[i];
    // init bbox arrays (uint4-per-batch, xyz used)
#pragma unroll
    for (int j = 0; j < 4; ++j) {
        bblo[tid * 4 + j] = 0xFFFFFFFFu;
        bbhi[tid * 4 + j] = 0u;
    }
}

// scatter into morton order + bbox maintenance via uint atomic min/max
__global__ void scatter_kernel(const float* __restrict__ coords, const float* __restrict__ scores,
                               const int* __restrict__ cellid, int* __restrict__ cursor,
                               float4* __restrict__ pk_s, float* __restrict__ s_s,
                               unsigned* __restrict__ bblo, unsigned* __restrict__ bbhi) {
    int i = blockIdx.x * 256 + threadIdx.x;
    if (i < NN) {
        int pos = atomicAdd(&cursor[cellid[i]], 1);
        float x = coords[3 * i], y = coords[3 * i + 1], z = coords[3 * i + 2];
        // MUST match dot ordering in knn_kernel so self-distance is exactly 0.
        float sq = fmaf(x, x, fmaf(y, y, z * z));
        pk_s[pos] = make_float4(x, y, z, sq);
        s_s[pos] = scores[i];
        const int b4 = (pos >> 4) * 4;
        atomicMin(&bblo[b4 + 0], fenc(x));
        atomicMin(&bblo[b4 + 1], fenc(y));
        atomicMin(&bblo[b4 + 2], fenc(z));
        atomicMax(&bbhi[b4 + 0], fenc(x));
        atomicMax(&bbhi[b4 + 1], fenc(y));
        atomicMax(&bbhi[b4 + 2], fenc(z));
    }
}

__device__ __forceinline__ void sort16(unsigned (&a)[16]) {
    // Batcher odd-even mergesort, ascending (verified R3-R8, absmax 0)
#pragma unroll
    for (int p2 = 1; p2 < 16; p2 <<= 1) {
#pragma unroll
        for (int k2 = p2; k2 >= 1; k2 >>= 1) {
#pragma unroll
            for (int j2 = k2 % p2; j2 + k2 < 16; j2 += 2 * k2) {
#pragma unroll
                for (int i2 = 0; i2 < k2; ++i2) {
                    if (i2 + j2 + k2 < 16) {
                        if (((i2 + j2) / (2 * p2)) == ((i2 + j2 + k2) / (2 * p2))) {
                            unsigned x = a[i2 + j2], y = a[i2 + j2 + k2];
                            a[i2 + j2]      = min(x, y);
                            a[i2 + j2 + k2] = max(x, y);
                        }
                    }
                }
            }
        }
    }
}

__device__ __forceinline__ void truncmerge(unsigned (&slot)[16], const unsigned (&kb)[16]) {
    // lowest-16 of (sorted slot ∪ sorted kb), result sorted (verified R3-R8)
    unsigned m[16];
#pragma unroll
    for (int k = 0; k < 16; ++k) m[k] = min(slot[k], kb[15 - k]);
#pragma unroll
    for (int st = 8; st >= 1; st >>= 1) {
#pragma unroll
        for (int i = 0; i < 16; ++i) {
            if ((i & st) == 0) {
                unsigned lo = min(m[i], m[i + st]);
                unsigned hi = max(m[i], m[i + st]);
                m[i] = lo; m[i + st] = hi;
            }
        }
    }
#pragma unroll
    for (int k = 0; k < 16; ++k) slot[k] = m[k];
}

// R5 structure + tight cooperative seed (verified R7/R8) + rank tail.
__global__ __launch_bounds__(1024) void knn_kernel(const float4* __restrict__ pk_s,
                                                   const float* __restrict__ s_s,
                                                   const unsigned* __restrict__ bblo,
                                                   const unsigned* __restrict__ bbhi,
                                                   int* __restrict__ out_idx,
                                                   int* __restrict__ out_rank) {
    __shared__ unsigned lds_k[16][16][64];  // [wave][slot][lane]: conflict-free
    __shared__ int lds_i[16][64];
    const int tid = threadIdx.x, lane = tid & 63;
    const int wv = __builtin_amdgcn_readfirstlane(tid >> 6);
    const int qbase = blockIdx.x * 64;
    const int cloudbase = (qbase >> 13) << 13;
    const float4 p = pk_s[qbase + lane];
    const int sb0 = (qbase - cloudbase) >> 4;      // first local batch (mult of 4)
    const int r = sb0 & 15;
    const int ownb = (wv >= r && wv < r + 4) ? (sb0 + (wv - r)) : -1;  // uniform
    const float4* __restrict__ pc = pk_s + cloudbase;
    const int bbase = cloudbase >> 4;

    unsigned slot[16];
#pragma unroll
    for (int k = 0; k < 16; ++k) slot[k] = 0x7F000000u + (unsigned)k;  // > any real key
    float t_f = 3.0e38f;

    auto batchU = [&](int bi) {
        unsigned kb[16];
#pragma unroll
        for (int i = 0; i < 16; ++i) {
            const int j = bi * 16 + i;             // uniform -> scalar loads
            const float4 c = pc[j];
            float dot = fmaf(p.x, c.x, fmaf(p.y, c.y, p.z * c.z));
            float d2  = fmaf(-2.0f, dot, p.w + c.w);   // exactly 0 for self
            kb[i] = (__float_as_uint(d2) & 0xFFFFE000u) | (unsigned)j;
        }
        sort16(kb);
        truncmerge(slot, kb);
        t_f = fminf(t_f, __uint_as_float((slot[15] & 0xFFFFE000u) + 0x2000u));
    };

    // --- tight cooperative seed (verified R7/R8) ---
    if (ownb >= 0) batchU(ownb);
#pragma unroll
    for (int k = 0; k < 16; ++k) lds_k[wv][k][lane] = slot[k];
    __syncthreads();
    unsigned mg[16];
#pragma unroll
    for (int k = 0; k < 16; ++k) mg[k] = lds_k[r][k][lane];
#pragma unroll
    for (int w2 = 1; w2 < 4; ++w2) {
        unsigned ob[16];
#pragma unroll
        for (int k = 0; k < 16; ++k) ob[k] = lds_k[r + w2][k][lane];
        truncmerge(mg, ob);
    }
    __syncthreads();   // all lds_k reads done before later writes
    if (wv == r) {
#pragma unroll
        for (int k = 0; k < 16; ++k) slot[k] = mg[k];
    } else {
#pragma unroll
        for (int k = 0; k < 16; ++k) slot[k] = 0x7F000000u + (unsigned)k;
    }
    t_f = __uint_as_float((mg[15] & 0xFFFFE000u) + 0x2000u);  // tight, tie-inclusive

    // --- bound scan with inline hot processing ---
    const uint4* __restrict__ blo4 = (const uint4*)bblo;
    const uint4* __restrict__ bhi4 = (const uint4*)bbhi;
    uint4 lo = blo4[bbase + wv];
    uint4 hi = bhi4[bbase + wv];
    for (int k2 = 0; k2 < 32; ++k2) {
        const int bi = wv + (k2 << 4);
        uint4 lo_n, hi_n;
        if (k2 + 1 < 32) {                         // uniform branch
            lo_n = blo4[bbase + bi + 16];
            hi_n = bhi4[bbase + bi + 16];
        }
        if (bi != ownb) {                          // uniform skip (seeded)
            float dx = fmaxf(fmaxf(fdec(lo.x) - p.x, p.x - fdec(hi.x)), 0.f);
            float dy = fmaxf(fmaxf(fdec(lo.y) - p.y, p.y - fdec(hi.y)), 0.f);
            float dz = fmaxf(fmaxf(fdec(lo.z) - p.z, p.z - fdec(hi.z)), 0.f);
            float lb = fmaf(dx, dx, fmaf(dy, dy, dz * dz));
            if (__any(fmaf(lb, 0.999f, -1e-5f) < t_f)) batchU(bi);
        }
        lo = lo_n; hi = hi_n;
    }

#pragma unroll
    for (int k = 0; k < 16; ++k) lds_k[wv][k][lane] = slot[k];

    // tree merge 16 -> 1 sorted lists (verified R3-R8)
    for (int half = 8; half >= 1; half >>= 1) {
        __syncthreads();
        if (wv < half) {
            unsigned a[16], m[16];
#pragma unroll
            for (int k = 0; k < 16; ++k) a[k] = lds_k[wv][k][lane];
#pragma unroll
            for (int k = 0; k < 16; ++k) m[k] = min(a[k], lds_k[wv + half][15 - k][lane]);
#pragma unroll
            for (int st = 8; st >= 1; st >>= 1) {
#pragma unroll
                for (int i = 0; i < 16; ++i) {
                    if ((i & st) == 0) {
                        unsigned lo2 = min(m[i], m[i + st]);
                        unsigned hi2 = max(m[i], m[i + st]);
                        m[i] = lo2; m[i + st] = hi2;
                    }
                }
            }
#pragma unroll
            for (int k = 0; k < 16; ++k) lds_k[wv][k][lane] = m[k];
        }
    }
    __syncthreads();
    if (wv == 0) {
#pragma unroll
        for (int k = 0; k < 16; ++k)
            out_idx[(qbase + lane) * 16 + k] = (int)(lds_k[0][k][lane] & 0x1FFFu) + cloudbase;
    }

    // --- rank tail (verbatim R5 rank body) ---
    {
        const float s = s_s[qbase + lane];
        const float* __restrict__ sc = s_s + cloudbase;
        int rank = 0;
        const int j0 = wv * 512;
        for (int jj = 0; jj < 512; jj += 16) {
#pragma unroll
            for (int i = 0; i < 16; ++i) {
                rank += (sc[j0 + jj + i] < s) ? 1 : 0;   // uniform -> scalar loads
            }
        }
        lds_i[wv][lane] = rank;
        __syncthreads();
        if (wv == 0) {
            int rsum = 0;
#pragma unroll
            for (int w = 0; w < 16; ++w) rsum += lds_i[w][lane];
            out_rank[qbase + lane] = rsum;
        }
    }
}

// one thread per (query,k) pair; block partials only (NO fences/atomics)
__global__ __launch_bounds__(256) void loss_kernel(const float* __restrict__ s_s,
                                                   const float4* __restrict__ pk_s,
                                                   const int* __restrict__ knn,
                                                   const int* __restrict__ rank,
                                                   float* __restrict__ partial) {
    __shared__ float red[4][6];
    const int t = blockIdx.x * 256 + threadIdx.x;
    const int q = t >> 4, k = t & 15;
    const int nb = knn[t];
    const float s  = s_s[q];
    const float sn = s_s[nb];
    const float diff = fabsf(s - sn);
    const float sim = 1.0f - diff;
    const float sg = 1.0f / (1.0f + expf(-2.0f * sim));

    float a_wd = 0.f, a_w = 0.f, a_pos = 0.f, a_neg = 0.f, snk = 0.f;
    if (k < 8) {
        float4 pq = pk_s[q];
        float4 pn = pk_s[nb];
        float dx = pq.x - pn.x, dy = pq.y - pn.y, dz = pq.z - pn.z;
        float d = sqrtf(dx * dx + dy * dy + dz * dz);
        float w = expf(-10.0f * d);
        a_wd = w * diff * diff;
        a_w  = w;
        a_pos = logf(sg + 1e-8f);
        snk = sn;
    } else {
        a_neg = logf(1.0f - sg + 1e-8f);
    }

    float nsum = snk;
#pragma unroll
    for (int off = 1; off < 16; off <<= 1) nsum += __shfl_xor(nsum, off);

    float a_sm = 0.f, a_di = 0.f;
    if (k == 0) {
        float t1 = s - nsum * 0.125f;
        a_sm = t1 * t1;
        float t2 = s - (float)rank[q] * (1.0f / 8191.0f);
        a_di = t2 * t2;
    }

#pragma unroll
    for (int off = 1; off < 64; off <<= 1) {
        a_wd  += __shfl_xor(a_wd, off);
        a_w   += __shfl_xor(a_w, off);
        a_pos += __shfl_xor(a_pos, off);
        a_neg += __shfl_xor(a_neg, off);
        a_sm  += __shfl_xor(a_sm, off);
        a_di  += __shfl_xor(a_di, off);
    }
    const int wv = threadIdx.x >> 6;
    if ((threadIdx.x & 63) == 0) {
        red[wv][0] = a_wd; red[wv][1] = a_w; red[wv][2] = a_pos;
        red[wv][3] = a_neg; red[wv][4] = a_sm; red[wv][5] = a_di;
    }
    __syncthreads();
    if (threadIdx.x < 6) {
        float v = red[0][threadIdx.x] + red[1][threadIdx.x] +
                  red[2][threadIdx.x] + red[3][threadIdx.x];
        partial[threadIdx.x * LOSS_BLOCKS + blockIdx.x] = v;
    }
}

__global__ __launch_bounds__(1024) void fin_kernel(const float* __restrict__ partial,
                                                   float* __restrict__ out) {
    __shared__ float red[16][6];
    const int tid = threadIdx.x;
    float a[6];
#pragma unroll
    for (int term = 0; term < 6; ++term) a[term] = partial[term * LOSS_BLOCKS + tid];
#pragma unroll
    for (int off = 1; off < 64; off <<= 1) {
#pragma unroll
        for (int term = 0; term < 6; ++term) a[term] += __shfl_xor(a[term], off);
    }
    if ((tid & 63) == 0) {
#pragma unroll
        for (int term = 0; term < 6; ++term) red[tid >> 6][term] = a[term];
    }
    __syncthreads();
    if (tid == 0) {
        float acc[6];
#pragma unroll
        for (int term = 0; term < 6; ++term) {
            float v = 0.f;
#pragma unroll
            for (int w = 0; w < 16; ++w) v += red[w][term];
            acc[term] = v;
        }
        float l_loc = acc[0] / fmaxf(acc[1], 1e-8f);
        float l_pos = -acc[2] / (float)(NN * 8);
        float l_neg = -acc[3] / (float)(NN * 8);
        float l_sm  = acc[4] / (float)NN;
        float l_di  = acc[5] / (float)NN;
        out[0] = l_loc + 0.5f * (l_pos + l_neg) + 0.3f * l_di + 0.2f * l_sm;
    }
}

extern "C" void kernel_launch(void* const* d_in, const int* in_sizes, int n_in,
                              void* d_out, int out_size, void* d_ws, size_t ws_size,
                              hipStream_t stream) {
    const float* scores = (const float*)d_in[0];
    const float* coords = (const float*)d_in[1];
    (void)in_sizes; (void)n_in; (void)out_size; (void)ws_size;

    char* ws = (char*)d_ws;
    float*    part  = (float*)(ws + PART_OFF);
    int*      rank  = (int*)(ws + RANK_OFF);
    int*      knn   = (int*)(ws + IDX_OFF);
    float4*   pk_s  = (float4*)(ws + PK_OFF);
    float*    s_s   = (float*)(ws + SS_OFF);
    int*      cellid= (int*)(ws + CELLID_OFF);
    int*      cursor= (int*)(ws + CUR_OFF);
    unsigned* bblo  = (unsigned*)(ws + BBLO_OFF);
    unsigned* bbhi  = (unsigned*)(ws + BBHI_OFF);
    float*    out   = (float*)d_out;

    countscan_kernel<<<1, 1024, 0, stream>>>(coords, cellid, cursor, bblo, bbhi);
    scatter_kernel<<<64, 256, 0, stream>>>(coords, scores, cellid, cursor, pk_s, s_s, bblo, bbhi);
    knn_kernel<<<256, 1024, 0, stream>>>(pk_s, s_s, bblo, bbhi, knn, rank);
    loss_kernel<<<LOSS_BLOCKS, 256, 0, stream>>>(s_s, pk_s, knn, rank, part);
    fin_kernel<<<1, 1024, 0, stream>>>(part, out);
}